// Round 7
// baseline (191.363 us; speedup 1.0000x reference)
//
#include <hip/hip_runtime.h>
#include <hip/hip_bf16.h>
#include <math.h>

#define B_TOT 16384
#define NPART 16
#define NPAIR 120     // 16*15/2
#define HID   64
#define DL    5
#define GB    4       // 4 waves/block, wave w <-> batch bg+w (fully independent)
#define SROWS 136     // per-wave s_f rows: 0..119 psi pairs, 120..135 phi

typedef __attribute__((ext_vector_type(8))) short short8;
typedef __attribute__((ext_vector_type(4))) float floatx4;

// Scale-fold constant: c = 1.702 * log2(e). Layer-1 W,b pre-scaled by c,
// layer-2 bias by c, 1/c folded into the readout column sums.
#define CSC      2.45556851f
#define INV_CSC  0.40723744f

// Single-instruction packed f32->bf16 convert (RNE).
__device__ __forceinline__ unsigned pk2(float a, float b) {
    unsigned r;
    asm("v_cvt_pk_bf16_f32 %0, %1, %2" : "=v"(r) : "v"(a), "v"(b));
    return r;
}

// pre-scaled gelu: input z = CSC * (true preact); returns CSC * gelu(true).
__device__ __forceinline__ float gelu_pre(float z) {
    float e = __builtin_amdgcn_exp2f(-z);
    return z * __builtin_amdgcn_rcpf(1.0f + e);
}

// unfolded form, used once in the rho readout only
__device__ __forceinline__ float gelu_sig(float v) {
    float e = __builtin_amdgcn_exp2f(-2.45556851f * v);
    return v * __builtin_amdgcn_rcpf(1.0f + e);
}

__device__ __forceinline__ float wred(float v) {
    v += __shfl_down(v, 32);
    v += __shfl_down(v, 16);
    v += __shfl_down(v, 8);
    v += __shfl_down(v, 4);
    v += __shfl_down(v, 2);
    v += __shfl_down(v, 1);
    return v;
}

// hidden-row permutation: tile ht, MFMA row m -> hidden index.
// Chosen so phase-1 D-frag lane (q,m15) holds exactly hiddens {q*8..q*8+7}
// (ht 0,1) and {32+q*8..+7} (ht 2,3) of M-row m15 -- i.e. precisely the
// k-slots its own phase-2 B-fragment needs. h1 never touches LDS.
__device__ __forceinline__ int hperm(int ht, int m) {
    return ((ht & 1) << 2) + ((ht >> 1) << 5) + ((m >> 2) << 3) + (m & 3);
}

// R17 = R16 with the register cap REMOVED. R16's __launch_bounds__(256,4)
// capped the unified VGPR+AGPR file at 128 (rocprof: vgpr 64 + agprs = 128,
// WRITE_SIZE 11.4MB of scratch spills, VALUBusy 61). Demand is ~150-190.
// Plain __launch_bounds__(256) lets the allocator take ~3 waves/SIMD with
// zero spills; no barriers + 16 indep acc chains keep issue fed at low occ.
// The sched_barrier(0) below is load-bearing: it keeps the phi-section
// fragments (~64 regs) out of the psi section's live range.
__global__ __launch_bounds__(256) void jastrow_wave2(
    const float* __restrict__ x,
    const float* __restrict__ phi_w0, const float* __restrict__ phi_b0,
    const float* __restrict__ phi_w1, const float* __restrict__ phi_b1,
    const float* __restrict__ phi_w2, const float* __restrict__ phi_b2,
    const float* __restrict__ psi_w0, const float* __restrict__ psi_b0,
    const float* __restrict__ psi_w1, const float* __restrict__ psi_b1,
    const float* __restrict__ psi_w2, const float* __restrict__ psi_b2,
    const float* __restrict__ rho_w0, const float* __restrict__ rho_b0,
    const float* __restrict__ rho_w1, const float* __restrict__ rho_b1,
    float* __restrict__ out)
{
    const int t    = threadIdx.x;
    const int lane = t & 63;
    const int wv   = t >> 6;
    const int q    = lane >> 4;
    const int m15  = lane & 15;
    const int bg   = blockIdx.x * GB;

    __shared__ __align__(16) unsigned short s_f[GB * SROWS * 8];  // 8704 B
    __shared__ float s_cs[GB * 2 * HID];                          // 2048 B
    unsigned short* sf = s_f + wv * SROWS * 8;

    const float2* x2 = (const float2*)x;
    const int bi = bg + wv;          // this wave's batch element
    float cusp = 0.f;

    // ================= Phase 0: features -> per-wave s_f ======================
    {
        {
            int p = lane;                     // 0..63
            int u = 119 - p;
            float sq = sqrtf((float)(8 * u + 1));
            int k = (int)((sq - 1.0f) * 0.5f);
            int i = 14 - k;
            int j = p - (i * (31 - i)) / 2 + i + 1;

            float2 xi = x2[bi * NPART + i];
            float2 xj = x2[bi * NPART + j];
            float dx = xi.x - xj.x, dy = xi.y - xj.y;
            float r = sqrtf(dx * dx + dy * dy + 1e-12f);

            float f0 = 0.69314718056f * __builtin_amdgcn_logf(1.f + r);
            float f1 = r * __builtin_amdgcn_rcpf(1.f + r);
            float f3 = __builtin_amdgcn_exp2f(-0.72134752044f * r);
            float f4 = f3 * f3;
            float f5 = f4 * f4;
            float f2 = __builtin_amdgcn_exp2f(-1.44269504089f * r * r);
            cusp += r * f4;                   // exact fp32

            union { short8 s; unsigned u4[4]; } v;
            v.u4[0] = pk2(f0, f1);
            v.u4[1] = pk2(f2, f3);
            v.u4[2] = pk2(f4, f5);
            v.u4[3] = pk2(1.0f, 0.f);         // k6 = 1.0 (bias slot), k7 = 0
            *(short8*)&sf[p * 8] = v.s;
        }
        if (lane < NPAIR - 64) {              // 56 more pairs
            int p = 64 + lane;
            int u = 119 - p;
            float sq = sqrtf((float)(8 * u + 1));
            int k = (int)((sq - 1.0f) * 0.5f);
            int i = 14 - k;
            int j = p - (i * (31 - i)) / 2 + i + 1;

            float2 xi = x2[bi * NPART + i];
            float2 xj = x2[bi * NPART + j];
            float dx = xi.x - xj.x, dy = xi.y - xj.y;
            float r = sqrtf(dx * dx + dy * dy + 1e-12f);

            float f0 = 0.69314718056f * __builtin_amdgcn_logf(1.f + r);
            float f1 = r * __builtin_amdgcn_rcpf(1.f + r);
            float f3 = __builtin_amdgcn_exp2f(-0.72134752044f * r);
            float f4 = f3 * f3;
            float f5 = f4 * f4;
            float f2 = __builtin_amdgcn_exp2f(-1.44269504089f * r * r);
            cusp += r * f4;

            union { short8 s; unsigned u4[4]; } v;
            v.u4[0] = pk2(f0, f1);
            v.u4[1] = pk2(f2, f3);
            v.u4[2] = pk2(f4, f5);
            v.u4[3] = pk2(1.0f, 0.f);
            *(short8*)&sf[p * 8] = v.s;
        }
        if (lane >= 48) {                     // 16 phi rows
            int n = lane - 48;
            float2 xv = x2[bi * NPART + n];
            float r2 = xv.x * xv.x + xv.y * xv.y;
            union { short8 s; unsigned u4[4]; } w;
            w.u4[0] = pk2(xv.x, xv.y);
            w.u4[1] = pk2(r2, 1.0f);          // k3 = 1.0 (bias slot)
            w.u4[2] = 0u; w.u4[3] = 0u;
            *(short8*)&sf[(120 + n) * 8] = w.s;
        }
    }
    float cusp_b;
    { float cc = wred(cusp); cusp_b = __shfl(cc, 0); }

    const floatx4 zf4 = {0.f, 0.f, 0.f, 0.f};

    // --------- psi fragments (permuted rows) ----------------------------------
    // A1p[ht]: q==0 lanes: W0 row hperm(ht,m15), k0..5 = CSC*w, k6 = CSC*b0.
    short8 A1p[4];
#pragma unroll
    for (int ht = 0; ht < 4; ++ht) {
        short8 f = (short8)0;
        if (q == 0) {
            int h = hperm(ht, m15);
            const float* w = psi_w0 + h * 6;
            union { short8 s; unsigned u4[4]; } bb;
            bb.u4[0] = pk2(CSC * w[0], CSC * w[1]);
            bb.u4[1] = pk2(CSC * w[2], CSC * w[3]);
            bb.u4[2] = pk2(CSC * w[4], CSC * w[5]);
            bb.u4[3] = pk2(CSC * psi_b0[h], 0.f);
            f = bb.s;
        }
        A1p[ht] = f;
    }
    // A2p[ht2][ks]: W1 row hperm(ht2,m15), k-slots = hidden (ks*32 + q*8 + j)
    // (identity in permuted hidden order). C1p[ht2] = CSC * b1 (permuted).
    short8 A2p[4][2];
    floatx4 C1p[4];
#pragma unroll
    for (int ht2 = 0; ht2 < 4; ++ht2) {
        int h2 = hperm(ht2, m15);
#pragma unroll
        for (int ks = 0; ks < 2; ++ks) {
            const floatx4* wp = (const floatx4*)(psi_w1 + h2 * HID + ks * 32 + q * 8);
            floatx4 wa = wp[0], wb = wp[1];
            union { short8 s; unsigned u4[4]; } bb;
            bb.u4[0] = pk2(wa[0], wa[1]); bb.u4[1] = pk2(wa[2], wa[3]);
            bb.u4[2] = pk2(wb[0], wb[1]); bb.u4[3] = pk2(wb[2], wb[3]);
            A2p[ht2][ks] = bb.s;
        }
        int cb = ((ht2 & 1) << 2) + ((ht2 >> 1) << 5) + (q << 3);
        floatx4 bv = *(const floatx4*)(psi_b1 + cb);
        C1p[ht2] = bv * CSC;
    }

    float CS[16];
#pragma unroll
    for (int i = 0; i < 16; ++i) CS[i] = 0.f;

    // ================= psi: 8 M-tiles, all in registers =======================
#pragma unroll
    for (int Mt = 0; Mt < 8; ++Mt) {
        short8 b = *(const short8*)&sf[(Mt * 16 + m15) * 8];
        floatx4 d0 = __builtin_amdgcn_mfma_f32_16x16x32_bf16(A1p[0], b, zf4, 0, 0, 0);
        floatx4 d1 = __builtin_amdgcn_mfma_f32_16x16x32_bf16(A1p[1], b, zf4, 0, 0, 0);
        union { short8 s; unsigned u4[4]; } Bk0, Bk1;
        Bk0.u4[0] = pk2(gelu_pre(d0[0]), gelu_pre(d0[1]));
        Bk0.u4[1] = pk2(gelu_pre(d0[2]), gelu_pre(d0[3]));
        Bk0.u4[2] = pk2(gelu_pre(d1[0]), gelu_pre(d1[1]));
        Bk0.u4[3] = pk2(gelu_pre(d1[2]), gelu_pre(d1[3]));
        floatx4 d2 = __builtin_amdgcn_mfma_f32_16x16x32_bf16(A1p[2], b, zf4, 0, 0, 0);
        floatx4 d3 = __builtin_amdgcn_mfma_f32_16x16x32_bf16(A1p[3], b, zf4, 0, 0, 0);
        Bk1.u4[0] = pk2(gelu_pre(d2[0]), gelu_pre(d2[1]));
        Bk1.u4[1] = pk2(gelu_pre(d2[2]), gelu_pre(d2[3]));
        Bk1.u4[2] = pk2(gelu_pre(d3[0]), gelu_pre(d3[1]));
        Bk1.u4[3] = pk2(gelu_pre(d3[2]), gelu_pre(d3[3]));

#pragma unroll
        for (int ht2 = 0; ht2 < 4; ++ht2) {
            floatx4 acc = __builtin_amdgcn_mfma_f32_16x16x32_bf16(A2p[ht2][0], Bk0.s, C1p[ht2], 0, 0, 0);
            acc = __builtin_amdgcn_mfma_f32_16x16x32_bf16(A2p[ht2][1], Bk1.s, acc, 0, 0, 0);
#pragma unroll
            for (int rg = 0; rg < 4; ++rg) {
                float z = acc[rg];
                float rr = __builtin_amdgcn_rcpf(1.0f + __builtin_amdgcn_exp2f(-z));
                if (Mt == 7) {
                    float p = z * rr;
                    p = (m15 < 8) ? p : 0.f;   // ghost M-rows 120..127
                    CS[ht2 * 4 + rg] += p;
                } else {
                    CS[ht2 * 4 + rg] = __builtin_fmaf(z, rr, CS[ht2 * 4 + rg]);
                }
            }
        }
    }

    // reduce colsums over the 16 m15 lanes (stays within each q-group)
#pragma unroll
    for (int i = 0; i < 16; ++i) {
        CS[i] += __shfl_xor(CS[i], 1);
        CS[i] += __shfl_xor(CS[i], 2);
        CS[i] += __shfl_xor(CS[i], 4);
        CS[i] += __shfl_xor(CS[i], 8);
    }
    // predicated store: lane m15==i writes CS[i] at its hidden2 index
#pragma unroll
    for (int i = 0; i < 16; ++i) {
        if (m15 == i) {
            int h2 = ((i >> 2) & 1) * 4 + (i >> 3) * 32 + q * 8 + (i & 3);
            s_cs[(wv * 2 + 0) * HID + h2] = CS[i];
        }
    }

    __builtin_amdgcn_sched_barrier(0);   // keep phi frag loads after psi loop

    // ================= phi: 1 M-tile (s_f rows 120..135) ======================
    {
        short8 A1f[4];
#pragma unroll
        for (int ht = 0; ht < 4; ++ht) {
            short8 f = (short8)0;
            if (q == 0) {
                int h = hperm(ht, m15);
                const float* w = phi_w0 + h * 3;
                union { short8 s; unsigned u4[4]; } bb;
                bb.u4[0] = pk2(CSC * w[0], CSC * w[1]);
                bb.u4[1] = pk2(CSC * w[2], CSC * phi_b0[h]);  // k3 = bias
                bb.u4[2] = 0u; bb.u4[3] = 0u;
                f = bb.s;
            }
            A1f[ht] = f;
        }
        short8 A2f[4][2];
        floatx4 C1f[4];
#pragma unroll
        for (int ht2 = 0; ht2 < 4; ++ht2) {
            int h2 = hperm(ht2, m15);
#pragma unroll
            for (int ks = 0; ks < 2; ++ks) {
                const floatx4* wp = (const floatx4*)(phi_w1 + h2 * HID + ks * 32 + q * 8);
                floatx4 wa = wp[0], wb = wp[1];
                union { short8 s; unsigned u4[4]; } bb;
                bb.u4[0] = pk2(wa[0], wa[1]); bb.u4[1] = pk2(wa[2], wa[3]);
                bb.u4[2] = pk2(wb[0], wb[1]); bb.u4[3] = pk2(wb[2], wb[3]);
                A2f[ht2][ks] = bb.s;
            }
            int cb = ((ht2 & 1) << 2) + ((ht2 >> 1) << 5) + (q << 3);
            floatx4 bv = *(const floatx4*)(phi_b1 + cb);
            C1f[ht2] = bv * CSC;
        }

        float CF[16];
        short8 b = *(const short8*)&sf[(120 + m15) * 8];
        floatx4 d0 = __builtin_amdgcn_mfma_f32_16x16x32_bf16(A1f[0], b, zf4, 0, 0, 0);
        floatx4 d1 = __builtin_amdgcn_mfma_f32_16x16x32_bf16(A1f[1], b, zf4, 0, 0, 0);
        union { short8 s; unsigned u4[4]; } Bk0, Bk1;
        Bk0.u4[0] = pk2(gelu_pre(d0[0]), gelu_pre(d0[1]));
        Bk0.u4[1] = pk2(gelu_pre(d0[2]), gelu_pre(d0[3]));
        Bk0.u4[2] = pk2(gelu_pre(d1[0]), gelu_pre(d1[1]));
        Bk0.u4[3] = pk2(gelu_pre(d1[2]), gelu_pre(d1[3]));
        floatx4 d2 = __builtin_amdgcn_mfma_f32_16x16x32_bf16(A1f[2], b, zf4, 0, 0, 0);
        floatx4 d3 = __builtin_amdgcn_mfma_f32_16x16x32_bf16(A1f[3], b, zf4, 0, 0, 0);
        Bk1.u4[0] = pk2(gelu_pre(d2[0]), gelu_pre(d2[1]));
        Bk1.u4[1] = pk2(gelu_pre(d2[2]), gelu_pre(d2[3]));
        Bk1.u4[2] = pk2(gelu_pre(d3[0]), gelu_pre(d3[1]));
        Bk1.u4[3] = pk2(gelu_pre(d3[2]), gelu_pre(d3[3]));

#pragma unroll
        for (int ht2 = 0; ht2 < 4; ++ht2) {
            floatx4 acc = __builtin_amdgcn_mfma_f32_16x16x32_bf16(A2f[ht2][0], Bk0.s, C1f[ht2], 0, 0, 0);
            acc = __builtin_amdgcn_mfma_f32_16x16x32_bf16(A2f[ht2][1], Bk1.s, acc, 0, 0, 0);
#pragma unroll
            for (int rg = 0; rg < 4; ++rg) {
                float z = acc[rg];
                float rr = __builtin_amdgcn_rcpf(1.0f + __builtin_amdgcn_exp2f(-z));
                CF[ht2 * 4 + rg] = z * rr;
            }
        }
#pragma unroll
        for (int i = 0; i < 16; ++i) {
            CF[i] += __shfl_xor(CF[i], 1);
            CF[i] += __shfl_xor(CF[i], 2);
            CF[i] += __shfl_xor(CF[i], 4);
            CF[i] += __shfl_xor(CF[i], 8);
        }
#pragma unroll
        for (int i = 0; i < 16; ++i) {
            if (m15 == i) {
                int h2 = ((i >> 2) & 1) * 4 + (i >> 3) * 32 + q * 8 + (i & 3);
                s_cs[(wv * 2 + 1) * HID + h2] = CF[i];
            }
        }
    }

    // ================= readout (per wave; same-wave LDS, no barrier) ==========
    {
        const int c = lane;
        float colP = s_cs[(wv * 2 + 0) * HID + c] * INV_CSC;
        float colF = s_cs[(wv * 2 + 1) * HID + c] * INV_CSC;

        float psiv[DL], phiv[DL];
#pragma unroll
        for (int d = 0; d < DL; ++d) {
            float sP = wred(colP * psi_w2[d * HID + c]);
            psiv[d] = __shfl(sP, 0) * (1.0f / NPAIR) + psi_b2[d];
            float sF = wred(colF * phi_w2[d * HID + c]);
            phiv[d] = __shfl(sF, 0) * (1.0f / NPART) + phi_b2[d];
        }

        int j = lane;
        float a = rho_b0[j];
        const float* wr = rho_w0 + j * (2 * DL);
#pragma unroll
        for (int d = 0; d < DL; ++d)
            a += phiv[d] * wr[d] + psiv[d] * wr[DL + d];
        float cv = gelu_sig(a) * rho_w1[j];
        cv = wred(cv);
        if (j == 0) out[bi] = cv + rho_b1[0] + cusp_b;
    }
}

extern "C" void kernel_launch(void* const* d_in, const int* in_sizes, int n_in,
                              void* d_out, int out_size, void* d_ws, size_t ws_size,
                              hipStream_t stream) {
    const float* x      = (const float*)d_in[0];
    const float* phi_w0 = (const float*)d_in[1];
    const float* phi_b0 = (const float*)d_in[2];
    const float* phi_w1 = (const float*)d_in[3];
    const float* phi_b1 = (const float*)d_in[4];
    const float* phi_w2 = (const float*)d_in[5];
    const float* phi_b2 = (const float*)d_in[6];
    const float* psi_w0 = (const float*)d_in[7];
    const float* psi_b0 = (const float*)d_in[8];
    const float* psi_w1 = (const float*)d_in[9];
    const float* psi_b1 = (const float*)d_in[10];
    const float* psi_w2 = (const float*)d_in[11];
    const float* psi_b2 = (const float*)d_in[12];
    const float* rho_w0 = (const float*)d_in[13];
    const float* rho_b0 = (const float*)d_in[14];
    const float* rho_w1 = (const float*)d_in[15];
    const float* rho_b1 = (const float*)d_in[16];

    jastrow_wave2<<<B_TOT / GB, 256, 0, stream>>>(
        x,
        phi_w0, phi_b0, phi_w1, phi_b1, phi_w2, phi_b2,
        psi_w0, psi_b0, psi_w1, psi_b1, psi_w2, psi_b2,
        rho_w0, rho_b0, rho_w1, rho_b1,
        (float*)d_out);
}

// Round 8
// 162.689 us; speedup vs baseline: 1.1762x; 1.1762x over previous
//
#include <hip/hip_runtime.h>
#include <hip/hip_bf16.h>
#include <math.h>

#define B_TOT 16384
#define NPART 16
#define NPAIR 120     // 16*15/2
#define HID   64
#define DL    5
#define GB    4       // batch elements per block (serialized through s_h)
#define PSI_ROWS 120  // psi h1 rows resident per iteration
#define PHI_HROW 120  // phi h1 rows live at s_h rows [120,136)
#define NROW_IT  136
#define SF_PHI   480  // phi feature rows in s_f at [480,544)

typedef __attribute__((ext_vector_type(8))) short short8;
typedef __attribute__((ext_vector_type(4))) float floatx4;

// Scale-fold constant: c = 1.702 * log2(e). Layer-1 W,b pre-scaled by c,
// layer-2 bias by c, 1/c folded into the readout column sums.
#define CSC      2.45556851f
#define INV_CSC  0.40723744f

// Single-instruction packed f32->bf16 convert (RNE): low16=cvt(a), high16=cvt(b).
// The hip_bf16 header's __float2bfloat16 is a multi-inst integer RNE sequence.
__device__ __forceinline__ unsigned pk2(float a, float b) {
    unsigned r;
    asm("v_cvt_pk_bf16_f32 %0, %1, %2" : "=v"(r) : "v"(a), "v"(b));
    return r;
}

// pre-scaled gelu: input z = CSC * (true preact); returns CSC * gelu(true).
// Scalar form kept deliberately (R4's packed-float2 variant raised VGPR 44->52
// and dropped occupancy 48->39.5, a net loss).
__device__ __forceinline__ float gelu_pre(float z) {
    float e = __builtin_amdgcn_exp2f(-z);
    return z * __builtin_amdgcn_rcpf(1.0f + e);
}

// unfolded form, used once in the rho readout only
__device__ __forceinline__ float gelu_sig(float v) {
    float e = __builtin_amdgcn_exp2f(-2.45556851f * v);
    return v * __builtin_amdgcn_rcpf(1.0f + e);
}

__device__ __forceinline__ float wred(float v) {
    v += __shfl_down(v, 32);
    v += __shfl_down(v, 16);
    v += __shfl_down(v, 8);
    v += __shfl_down(v, 4);
    v += __shfl_down(v, 2);
    v += __shfl_down(v, 1);
    return v;
}

// Block = 4 batch elements, 256 threads (4 waves). LDS ~26.1 KB -> 6 blocks/CU.
// h1 LDS: s_h[row*64 + (col ^ ((row&7)<<3))] (16B-granular XOR swizzle; proven
// 262K-conflict pattern). Layer-1/2 via MFMA 16x16x32 bf16, col-split across
// waves; layer-3 folded into column sums. Cusp exact fp32.
// R18 = R13 (95.3us, best) + asm-pk2 ONLY. A/B vs R4 (pk2+packed gelu, 97.6,
// occ 39.5): isolates whether packed gelu or asm pk2 caused R4's VGPR jump.
// R16/R17 wave-autonomous branch abandoned (latency-bound at low occupancy).
__global__ __launch_bounds__(256) void jastrow_mfma14(
    const float* __restrict__ x,
    const float* __restrict__ phi_w0, const float* __restrict__ phi_b0,
    const float* __restrict__ phi_w1, const float* __restrict__ phi_b1,
    const float* __restrict__ phi_w2, const float* __restrict__ phi_b2,
    const float* __restrict__ psi_w0, const float* __restrict__ psi_b0,
    const float* __restrict__ psi_w1, const float* __restrict__ psi_b1,
    const float* __restrict__ psi_w2, const float* __restrict__ psi_b2,
    const float* __restrict__ rho_w0, const float* __restrict__ rho_b0,
    const float* __restrict__ rho_w1, const float* __restrict__ rho_b1,
    float* __restrict__ out)
{
    const int t    = threadIdx.x;
    const int lane = t & 63;
    const int wv   = t >> 6;
    const int q    = lane >> 4;
    const int m15  = lane & 15;
    const int bg   = blockIdx.x * GB;

    __shared__ __align__(16) unsigned short s_h[NROW_IT * 64];   // 17408 B
    __shared__ __align__(16) unsigned char  s_mem[8704];         // s_f | s_cs
    __shared__ float s_cusp[GB];

    unsigned short* s_f  = (unsigned short*)s_mem;  // [544][8] bf16 features
    float*          s_cs = (float*)s_mem;           // [2][GB][4][4][16] colsum partials

    const float2* x2 = (const float2*)x;
    float cusp = 0.f;

    // ================= Phase 0: features (all 4 batches) -> s_f ================
    // wave wv owns batch wv: pair p=lane (all 64), p=64+lane (lane<56),
    // phi rows n=lane-48 (lane>=48).
    {
        const int bl = wv;
        {
            int p = lane;                     // 0..63, always < NPAIR
            int u = 119 - p;
            float sq = sqrtf((float)(8 * u + 1));
            int k = (int)((sq - 1.0f) * 0.5f);
            int i = 14 - k;
            int j = p - (i * (31 - i)) / 2 + i + 1;

            float2 xi = x2[(bg + bl) * NPART + i];
            float2 xj = x2[(bg + bl) * NPART + j];
            float dx = xi.x - xj.x, dy = xi.y - xj.y;
            float r = sqrtf(dx * dx + dy * dy + 1e-12f);

            float f0 = 0.69314718056f * __builtin_amdgcn_logf(1.f + r);
            float f1 = r * __builtin_amdgcn_rcpf(1.f + r);
            float f3 = __builtin_amdgcn_exp2f(-0.72134752044f * r);
            float f4 = f3 * f3;
            float f5 = f4 * f4;
            float f2 = __builtin_amdgcn_exp2f(-1.44269504089f * r * r);
            cusp += r * f4;                   // exact fp32

            union { short8 s; unsigned u4[4]; } v;
            v.u4[0] = pk2(f0, f1);
            v.u4[1] = pk2(f2, f3);
            v.u4[2] = pk2(f4, f5);
            v.u4[3] = 0u;
            *(short8*)&s_f[(bl * PSI_ROWS + p) * 8] = v.s;
        }
        if (lane < NPAIR - 64) {              // 56 more pairs
            int p = 64 + lane;
            int u = 119 - p;
            float sq = sqrtf((float)(8 * u + 1));
            int k = (int)((sq - 1.0f) * 0.5f);
            int i = 14 - k;
            int j = p - (i * (31 - i)) / 2 + i + 1;

            float2 xi = x2[(bg + bl) * NPART + i];
            float2 xj = x2[(bg + bl) * NPART + j];
            float dx = xi.x - xj.x, dy = xi.y - xj.y;
            float r = sqrtf(dx * dx + dy * dy + 1e-12f);

            float f0 = 0.69314718056f * __builtin_amdgcn_logf(1.f + r);
            float f1 = r * __builtin_amdgcn_rcpf(1.f + r);
            float f3 = __builtin_amdgcn_exp2f(-0.72134752044f * r);
            float f4 = f3 * f3;
            float f5 = f4 * f4;
            float f2 = __builtin_amdgcn_exp2f(-1.44269504089f * r * r);
            cusp += r * f4;

            union { short8 s; unsigned u4[4]; } v;
            v.u4[0] = pk2(f0, f1);
            v.u4[1] = pk2(f2, f3);
            v.u4[2] = pk2(f4, f5);
            v.u4[3] = 0u;
            *(short8*)&s_f[(bl * PSI_ROWS + p) * 8] = v.s;
        }
        if (lane >= 48) {                     // 16 phi rows of this wave's batch
            int n = lane - 48;
            float2 xv = x2[(bg + bl) * NPART + n];
            float r2 = xv.x * xv.x + xv.y * xv.y;
            union { short8 s; unsigned u4[4]; } w;
            w.u4[0] = pk2(xv.x, xv.y);
            w.u4[1] = pk2(r2, 0.f);
            w.u4[2] = 0u; w.u4[3] = 0u;
            *(short8*)&s_f[(SF_PHI + bl * NPART + n) * 8] = w.s;
        }
    }

    const int colb = wv * 16 + m15;           // this lane's output column
    int swz[4];
#pragma unroll
    for (int rg = 0; rg < 4; ++rg) swz[rg] = colb ^ (((q * 4 + rg) & 7) << 3);

    // --------- hoisted B-fragments + biases (live across all iterations) -------
    short8 Bp1 = (short8)0, Bf1 = (short8)0;
    if (q == 0) {
        union { short8 s; unsigned u4[4]; } bb;
        const float* w = psi_w0 + colb * 6;
        bb.u4[0] = pk2(CSC * w[0], CSC * w[1]);
        bb.u4[1] = pk2(CSC * w[2], CSC * w[3]);
        bb.u4[2] = pk2(CSC * w[4], CSC * w[5]);
        bb.u4[3] = 0u;
        Bp1 = bb.s;
        const float* wf = phi_w0 + colb * 3;
        bb.u4[0] = pk2(CSC * wf[0], CSC * wf[1]);
        bb.u4[1] = pk2(CSC * wf[2], 0.f);
        bb.u4[2] = 0u; bb.u4[3] = 0u;
        Bf1 = bb.s;
    }
    float b0p = CSC * psi_b0[colb], b0f = CSC * phi_b0[colb];
    floatx4 C0p = {b0p, b0p, b0p, b0p};
    floatx4 C0f = {b0f, b0f, b0f, b0f};

    short8 Bp2[2], Bf2[2];
#pragma unroll
    for (int Kc = 0; Kc < 2; ++Kc) {
        const floatx4* wp4 = (const floatx4*)(psi_w1 + colb * HID + Kc * 32 + q * 8);
        const floatx4* wf4 = (const floatx4*)(phi_w1 + colb * HID + Kc * 32 + q * 8);
        floatx4 pA = wp4[0], pB = wp4[1];
        floatx4 fA = wf4[0], fB = wf4[1];
        union { short8 s; unsigned u4[4]; } bp, bf;
        bp.u4[0] = pk2(pA[0], pA[1]); bp.u4[1] = pk2(pA[2], pA[3]);
        bp.u4[2] = pk2(pB[0], pB[1]); bp.u4[3] = pk2(pB[2], pB[3]);
        bf.u4[0] = pk2(fA[0], fA[1]); bf.u4[1] = pk2(fA[2], fA[3]);
        bf.u4[2] = pk2(fB[0], fB[1]); bf.u4[3] = pk2(fB[2], fB[3]);
        Bp2[Kc] = bp.s; Bf2[Kc] = bf.s;
    }
    float b1p = CSC * psi_b1[colb], b1f = CSC * phi_b1[colb];
    floatx4 C1p = {b1p, b1p, b1p, b1p};
    floatx4 C1f = {b1f, b1f, b1f, b1f};

    // swizzled A-read offsets for layer-2 (row&7 = m15&7; all row bases %8==0)
    const int g0 = ((q ^ (m15 & 7)) << 3);
    const int g1 = g0 ^ 32;

    float csP[GB] = {0.f, 0.f, 0.f, 0.f};
    float csF[GB] = {0.f, 0.f, 0.f, 0.f};

    __syncthreads();   // s_f ready

    // ================= serialized per-batch iterations =========================
#pragma unroll
    for (int bl = 0; bl < GB; ++bl) {
        // ---- Phase 1: layer-1 MFMA + gelu + swizzled scatter into s_h --------
        // Store prep: 2x v_cvt_pk_bf16_f32 + 2 shifts (was 4x header converts).
#pragma unroll
        for (int Mt = 0; Mt < 8; ++Mt) {
            short8 a = *(const short8*)&s_f[(bl * PSI_ROWS + Mt * 16 + m15) * 8];
            floatx4 d = __builtin_amdgcn_mfma_f32_16x16x32_bf16(a, Bp1, C0p, 0, 0, 0);
            if (Mt < 7 || q < 2) {   // D-rows 120..127 don't exist -> skip
                unsigned u01 = pk2(gelu_pre(d[0]), gelu_pre(d[1]));
                unsigned u23 = pk2(gelu_pre(d[2]), gelu_pre(d[3]));
                s_h[(Mt * 16 + q * 4 + 0) * 64 + swz[0]] = (unsigned short)u01;
                s_h[(Mt * 16 + q * 4 + 1) * 64 + swz[1]] = (unsigned short)(u01 >> 16);
                s_h[(Mt * 16 + q * 4 + 2) * 64 + swz[2]] = (unsigned short)u23;
                s_h[(Mt * 16 + q * 4 + 3) * 64 + swz[3]] = (unsigned short)(u23 >> 16);
            }
        }
        {
            short8 a = *(const short8*)&s_f[(SF_PHI + bl * NPART + m15) * 8];
            floatx4 d = __builtin_amdgcn_mfma_f32_16x16x32_bf16(a, Bf1, C0f, 0, 0, 0);
            unsigned u01 = pk2(gelu_pre(d[0]), gelu_pre(d[1]));
            unsigned u23 = pk2(gelu_pre(d[2]), gelu_pre(d[3]));
            s_h[(PHI_HROW + q * 4 + 0) * 64 + swz[0]] = (unsigned short)u01;
            s_h[(PHI_HROW + q * 4 + 1) * 64 + swz[1]] = (unsigned short)(u01 >> 16);
            s_h[(PHI_HROW + q * 4 + 2) * 64 + swz[2]] = (unsigned short)u23;
            s_h[(PHI_HROW + q * 4 + 3) * 64 + swz[3]] = (unsigned short)(u23 >> 16);
        }
        __syncthreads();   // h1 ready

        // ---- Phase 2+3: layer-2 MFMA + gelu + colsum accumulate ---------------
#pragma unroll
        for (int Mt = 0; Mt < 8; ++Mt) {
            int rb = (Mt * 16 + m15) * 64;
            short8 a0 = *(const short8*)&s_h[rb + g0];
            short8 a1 = *(const short8*)&s_h[rb + g1];
            floatx4 acc = __builtin_amdgcn_mfma_f32_16x16x32_bf16(a0, Bp2[0], C1p, 0, 0, 0);
            acc = __builtin_amdgcn_mfma_f32_16x16x32_bf16(a1, Bp2[1], acc, 0, 0, 0);
            if (Mt == 7) {
                if (q < 2) {       // D-rows 120..127 are garbage -> exclude
#pragma unroll
                    for (int rg = 0; rg < 4; ++rg) {
                        float z = acc[rg];
                        float rr = __builtin_amdgcn_rcpf(1.0f + __builtin_amdgcn_exp2f(-z));
                        csP[bl] = __builtin_fmaf(z, rr, csP[bl]);
                    }
                }
            } else {
#pragma unroll
                for (int rg = 0; rg < 4; ++rg) {
                    float z = acc[rg];
                    float rr = __builtin_amdgcn_rcpf(1.0f + __builtin_amdgcn_exp2f(-z));
                    csP[bl] = __builtin_fmaf(z, rr, csP[bl]);
                }
            }
        }
        {
            int rb = (PHI_HROW + m15) * 64;
            short8 a0 = *(const short8*)&s_h[rb + g0];
            short8 a1 = *(const short8*)&s_h[rb + g1];
            floatx4 acc = __builtin_amdgcn_mfma_f32_16x16x32_bf16(a0, Bf2[0], C1f, 0, 0, 0);
            acc = __builtin_amdgcn_mfma_f32_16x16x32_bf16(a1, Bf2[1], acc, 0, 0, 0);
#pragma unroll
            for (int rg = 0; rg < 4; ++rg) {
                float z = acc[rg];
                float rr = __builtin_amdgcn_rcpf(1.0f + __builtin_amdgcn_exp2f(-z));
                csF[bl] = __builtin_fmaf(z, rr, csF[bl]);
            }
        }
        if (bl < GB - 1) __syncthreads();   // s_h consumed; safe to overwrite
    }

    // ---- store colsum partials (s_f dead -> s_cs aliases it) ------------------
#pragma unroll
    for (int bl = 0; bl < GB; ++bl) {
        s_cs[(((0 * GB + bl) * 4 + wv) * 4 + q) * 16 + m15] = csP[bl];
        s_cs[(((1 * GB + bl) * 4 + wv) * 4 + q) * 16 + m15] = csF[bl];
    }
    {
        float cc = wred(cusp);
        if (lane == 0) s_cusp[wv] = cc;   // wave wv == batch wv cusp total
    }
    __syncthreads();

    // ================= Phase 4: readout (wave w -> batch w) ====================
    {
        const int blr = wv;
        const int c   = lane;
        const int cw  = c >> 4, cm = c & 15;
        float colP = 0.f, colF = 0.f;
#pragma unroll
        for (int qq = 0; qq < 4; ++qq) {
            colP += s_cs[(((0 * GB + blr) * 4 + cw) * 4 + qq) * 16 + cm];
            colF += s_cs[(((1 * GB + blr) * 4 + cw) * 4 + qq) * 16 + cm];
        }
        colP *= INV_CSC;   // undo the scale-fold of the hidden gelu
        colF *= INV_CSC;

        float psiv[DL], phiv[DL];
#pragma unroll
        for (int d = 0; d < DL; ++d) {
            float sP = wred(colP * psi_w2[d * HID + c]);
            psiv[d] = __shfl(sP, 0) * (1.0f / NPAIR) + psi_b2[d];
            float sF = wred(colF * phi_w2[d * HID + c]);
            phiv[d] = __shfl(sF, 0) * (1.0f / NPART) + phi_b2[d];
        }

        int j = lane;
        float a = rho_b0[j];
        const float* wr = rho_w0 + j * (2 * DL);
#pragma unroll
        for (int d = 0; d < DL; ++d)
            a += phiv[d] * wr[d] + psiv[d] * wr[DL + d];
        float cuspb = s_cusp[blr];
        float cv = gelu_sig(a) * rho_w1[j];
        cv = wred(cv);
        if (j == 0) out[bg + blr] = cv + rho_b1[0] + cuspb;
    }
}

extern "C" void kernel_launch(void* const* d_in, const int* in_sizes, int n_in,
                              void* d_out, int out_size, void* d_ws, size_t ws_size,
                              hipStream_t stream) {
    const float* x      = (const float*)d_in[0];
    const float* phi_w0 = (const float*)d_in[1];
    const float* phi_b0 = (const float*)d_in[2];
    const float* phi_w1 = (const float*)d_in[3];
    const float* phi_b1 = (const float*)d_in[4];
    const float* phi_w2 = (const float*)d_in[5];
    const float* phi_b2 = (const float*)d_in[6];
    const float* psi_w0 = (const float*)d_in[7];
    const float* psi_b0 = (const float*)d_in[8];
    const float* psi_w1 = (const float*)d_in[9];
    const float* psi_b1 = (const float*)d_in[10];
    const float* psi_w2 = (const float*)d_in[11];
    const float* psi_b2 = (const float*)d_in[12];
    const float* rho_w0 = (const float*)d_in[13];
    const float* rho_b0 = (const float*)d_in[14];
    const float* rho_w1 = (const float*)d_in[15];
    const float* rho_b1 = (const float*)d_in[16];

    jastrow_mfma14<<<B_TOT / GB, 256, 0, stream>>>(
        x,
        phi_w0, phi_b0, phi_w1, phi_b1, phi_w2, phi_b2,
        psi_w0, psi_b0, psi_w1, psi_b1, psi_w2, psi_b2,
        rho_w0, rho_b0, rho_w1, rho_b1,
        (float*)d_out);
}